// Round 3
// baseline (144.190 us; speedup 1.0000x reference)
//
#include <hip/hip_runtime.h>
#include <math.h>

#define KS     65536
#define TS     96
#define RT_TPB 512
#define WPB    (RT_TPB / 64)     /* 8 samples (waves) per rollout block */
#define NBLK2  (KS / WPB)        /* 8192 rollout blocks */
#define W_TPB  256
#define W_NBLK (KS / W_TPB)      /* 256 weight blocks */

#define MSR 0.196f               /* 9.8 * 0.02 (f64 -> f32) */
#define WSM 17.0f
#define DTF 0.02f

static __device__ __forceinline__ float clampf(float v, float lo, float hi) {
  return fminf(fmaxf(v, lo), hi);
}

/* ws layout (floats):
   [0, KS*4)              per-k {cost_total, noise[k,0,0], noise[k,0,1], pad}
   [KS*4, KS*4+NBLK2)     per-block cost min (8192)
   [KS*4+NBLK2, +3)       accumulators {sum_w, sum_w*n0, sum_w*n1}          */

__global__ __launch_bounds__(RT_TPB) void mppi_rollout(
    const float* __restrict__ state, const float* __restrict__ U,
    const float* __restrict__ noise, const float* __restrict__ nsi,
    const float* __restrict__ bev,   const float* __restrict__ goal,
    float* __restrict__ ws)
{
  /* MAX_CURV_RATE exactly as the reference: f64 chain, rounded to f32 once */
  const float MCR = (float)(tan(30.0 / 57.3) / (0.24 + 0.24) * 20.0 * 0.02);

  __shared__ float  s_bev[2500];
  __shared__ float4 s_uv4[48];   /* {u0[2l],u1[2l],u0[2l+1],u1[2l+1]} */
  __shared__ float4 s_g4[48];    /* {g0[2l],g1[2l],g0[2l+1],g1[2l+1]} */
  __shared__ float  s_min[WPB];

  const int tid = threadIdx.x;
  if (tid < TS) {
    float u0 = 0.f, u1 = 0.f;
    if (tid < TS - 1) { u0 = U[(tid + 1) * 2 + 0]; u1 = U[(tid + 1) * 2 + 1]; }
    float2 a; a.x = u0; a.y = u1;
    ((float2*)s_uv4)[tid] = a;
    float2 b; b.x = u0 * nsi[0] + u1 * nsi[1]; b.y = u0 * nsi[2] + u1 * nsi[3];
    ((float2*)s_g4)[tid] = b;
  }
  for (int i = tid; i < 2500; i += RT_TPB) s_bev[i] = bev[i];
  if (blockIdx.x == 0 && tid < 3) ws[(size_t)KS * 4 + NBLK2 + tid] = 0.f;
  __syncthreads();

  const int wid  = tid >> 6, lane = tid & 63;
  const int k    = blockIdx.x * WPB + wid;
  const bool act = (lane < 48);          /* lane l owns t = 2l, 2l+1 (t<96) */

  float4 v;  v.x = v.y = v.z = v.w = 0.f;
  float4 uv; uv.x = uv.y = uv.z = uv.w = 0.f;
  float4 g4; g4.x = g4.y = g4.z = g4.w = 0.f;
  if (act) {
    v  = ((const float4*)(noise + (size_t)k * (TS * 2)))[lane];
    uv = s_uv4[lane];
    g4 = s_g4[lane];
  }

  /* raw (pre-rate-limit) curvature/speed at t0, t1 */
  float cr0 = (uv.x + v.x) * MCR, sr0 = (uv.y + v.y) * WSM;
  float cr1 = (uv.z + v.z) * MCR, sr1 = (uv.w + v.w) * WSM;

  /* clipped diffs: dc[t] = clip(raw[t+1]-raw[t]); raw[2l+2] via shfl */
  float crN = __shfl_down(cr0, 1), srN = __shfl_down(sr0, 1);
  float dc0 = clampf(cr1 - cr0, -MCR, MCR), dc1 = clampf(crN - cr1, -MCR, MCR);
  float ds0 = clampf(sr1 - sr0, -MSR, MSR), ds1 = clampf(srN - sr1, -MSR, MSR);
  if (lane >= 47) { dc1 = 0.f; ds1 = 0.f; }   /* t=95 excluded from cumsum */
  if (!act)       { dc0 = 0.f; ds0 = 0.f; }

  /* wave-parallel inclusive scans for c and s (interleaved) */
  float cB = dc0 + dc1, sB = ds0 + ds1;
  float cS = cB, sS = sB;
  #pragma unroll
  for (int d = 1; d < 64; d <<= 1) {
    float oc = __shfl_up(cS, d), os = __shfl_up(sS, d);
    if (lane >= d) { cS += oc; sS += os; }
  }
  float cexcl = cS - cB, sexcl = sS - sB;
  float c0 = cexcl + dc0, c1 = cexcl + cB;
  float s0 = sexcl + ds0, s1 = sexcl + sB;
  if (lane == 47) { c1 = cr1; s1 = sr1; }   /* c[:, :, -1:] = raw last */

  /* yaw scan */
  float yi0 = s0 * c0 * DTF, yi1 = s1 * c1 * DTF;
  float yB = yi0 + yi1, yS = yB;
  #pragma unroll
  for (int d = 1; d < 64; d <<= 1) {
    float o = __shfl_up(yS, d);
    if (lane >= d) yS += o;
  }
  const float st5 = state[5];
  float yexcl = yS - yB;
  float yaw0 = st5 + (yexcl + yi0), yaw1 = st5 + (yexcl + yB);

  float sn0, co0, sn1, co1;
  sincosf(yaw0, &sn0, &co0);
  sincosf(yaw1, &sn1, &co1);

  /* x and y scans (interleaved) */
  float xi0 = s0 * co0 * DTF, xi1 = s1 * co1 * DTF;
  float pi0 = s0 * sn0 * DTF, pi1 = s1 * sn1 * DTF;
  float xB = xi0 + xi1, pB = pi0 + pi1;
  float xS = xB, pS = pB;
  #pragma unroll
  for (int d = 1; d < 64; d <<= 1) {
    float ox = __shfl_up(xS, d), op = __shfl_up(pS, d);
    if (lane >= d) { xS += ox; pS += op; }
  }
  const float stx = state[0], sty = state[1];
  float x0 = stx + (xS - xB + xi0), x1 = stx + (xS - xB + xB);
  float p0 = sty + (pS - pB + pi0), p1 = sty + (pS - pB + pB);

  /* per-t running cost + action cost */
  const float gx = goal[0], gy = goal[1];
  float part = 0.f, dist1 = 0.f;
  {
    float dx = x0 - gx, dy = p0 - gy;
    float d0 = sqrtf(dx * dx + dy * dy);
    int ix = (int)(x0 / 0.4f + 25.f), iy = (int)(p0 / 0.4f + 25.f);
    ix = min(max(ix, 0), 49); iy = min(max(iy, 0), 49);
    part += s_bev[iy * 50 + ix] + 0.1f * d0;

    dx = x1 - gx; dy = p1 - gy;
    dist1 = sqrtf(dx * dx + dy * dy);
    ix = (int)(x1 / 0.4f + 25.f); iy = (int)(p1 / 0.4f + 25.f);
    ix = min(max(ix, 0), 49); iy = min(max(iy, 0), 49);
    part += s_bev[iy * 50 + ix] + 0.1f * dist1;

    part += v.x * g4.x + v.y * g4.y + v.z * g4.z + v.w * g4.w;
  }
  if (!act) part = 0.f;
  if (lane == 47) part += dist1;          /* terminal = dist at t=95 */

  /* wave sum -> cost_total on all lanes */
  #pragma unroll
  for (int d = 1; d < 64; d <<= 1) part += __shfl_xor(part, d);

  if (lane == 0) {
    float4 o; o.x = part; o.y = v.x; o.z = v.y; o.w = 0.f;
    ((float4*)ws)[k] = o;
    s_min[wid] = part;
  }
  __syncthreads();
  if (tid == 0) {
    float m = s_min[0];
    for (int w = 1; w < WPB; ++w) m = fminf(m, s_min[w]);
    ws[(size_t)KS * 4 + blockIdx.x] = m;
  }
}

__global__ __launch_bounds__(W_TPB) void mppi_weight(
    const float* __restrict__ ws, float* __restrict__ acc)
{
  const int tid = threadIdx.x;
  /* beta: every block redundantly reduces the 8192 block mins (L2-hot) */
  const float* mins = ws + (size_t)KS * 4;
  float m = 3.4028235e38f;
  for (int i = tid; i < NBLK2; i += W_TPB) m = fminf(m, mins[i]);
  #pragma unroll
  for (int off = 32; off >= 1; off >>= 1) m = fminf(m, __shfl_xor(m, off));
  __shared__ float s_m[W_TPB / 64];
  if ((tid & 63) == 0) s_m[tid >> 6] = m;
  __syncthreads();
  const float beta = fminf(fminf(s_m[0], s_m[1]), fminf(s_m[2], s_m[3]));

  const int k = blockIdx.x * W_TPB + tid;
  const float4 v = ((const float4*)ws)[k];
  const float w = expf(beta - v.x);   /* exp(-(cost-beta)/LAMBDA), LAMBDA=1 */
  float s0 = w, s1 = w * v.y, s2 = w * v.z;
  #pragma unroll
  for (int off = 32; off >= 1; off >>= 1) {
    s0 += __shfl_xor(s0, off);
    s1 += __shfl_xor(s1, off);
    s2 += __shfl_xor(s2, off);
  }
  __shared__ float s_p[W_TPB / 64][3];
  if ((tid & 63) == 0) { s_p[tid >> 6][0] = s0; s_p[tid >> 6][1] = s1; s_p[tid >> 6][2] = s2; }
  __syncthreads();
  if (tid == 0) {
    float a0 = 0.f, a1 = 0.f, a2 = 0.f;
    for (int w2 = 0; w2 < W_TPB / 64; ++w2) { a0 += s_p[w2][0]; a1 += s_p[w2][1]; a2 += s_p[w2][2]; }
    atomicAdd(&acc[0], a0); atomicAdd(&acc[1], a1); atomicAdd(&acc[2], a2);
  }
}

__global__ void mppi_final(const float* __restrict__ U,
                           const float* __restrict__ acc,
                           float* __restrict__ out)
{
  if (threadIdx.x == 0) {
    const float inv = 1.0f / acc[0];
    out[0] = U[2] + acc[1] * inv;   /* U_rolled[0] = U_orig[1] */
    out[1] = U[3] + acc[2] * inv;
  }
}

extern "C" void kernel_launch(void* const* d_in, const int* in_sizes, int n_in,
                              void* d_out, int out_size, void* d_ws, size_t ws_size,
                              hipStream_t stream)
{
  const float* state = (const float*)d_in[0];
  const float* U     = (const float*)d_in[1];
  const float* noise = (const float*)d_in[2];
  const float* nsi   = (const float*)d_in[3];
  const float* bev   = (const float*)d_in[4];
  const float* goal  = (const float*)d_in[5];
  /* d_in[6] (last_action) only writes state[15:17] -> never affects output */

  float* ws  = (float*)d_ws;
  float* out = (float*)d_out;
  float* acc = ws + (size_t)KS * 4 + NBLK2;

  mppi_rollout<<<NBLK2, RT_TPB, 0, stream>>>(state, U, noise, nsi, bev, goal, ws);
  mppi_weight<<<W_NBLK, W_TPB, 0, stream>>>(ws, acc);
  mppi_final<<<1, 64, 0, stream>>>(U, acc, out);
}

// Round 4
// 119.032 us; speedup vs baseline: 1.2114x; 1.2114x over previous
//
#include <hip/hip_runtime.h>
#include <math.h>

#define KS    65536
#define TS    96
#define TPB   256
#define NBLK  (KS / TPB)      /* 256 */

#define MSR 0.196f            /* 9.8 * 0.02 (f64 -> f32) */
#define WSM 17.0f
#define DTF 0.02f

/* Branchless sincos: Cody-Waite pi/2 reduction (fma, 3 words) + Taylor
   deg-7 sin / deg-8 cos on [-pi/4,pi/4]. |err| ~ 1e-7 for |x| < ~6000 rad. */
static __device__ __forceinline__ void fast_sincosf(float x, float& s, float& c) {
  float nf = __builtin_rintf(x * 0.63661977f);
  int   q  = (int)nf;
  float r  = __builtin_fmaf(nf, -1.5703125f, x);
  r = __builtin_fmaf(nf, -4.837512969970703125e-4f, r);
  r = __builtin_fmaf(nf, -7.54978995489188216e-8f, r);
  float r2 = r * r;
  float sw = __builtin_fmaf(r2, -1.98412698e-4f, 8.33333310e-3f);
  sw = __builtin_fmaf(r2, sw, -1.66666672e-1f);
  sw = __builtin_fmaf(r2, sw, 1.0f);
  float sinr = r * sw;
  float cw = __builtin_fmaf(r2, 2.48015873e-5f, -1.38888889e-3f);
  cw = __builtin_fmaf(r2, cw, 4.16666679e-2f);
  cw = __builtin_fmaf(r2, cw, -0.5f);
  float cosr = __builtin_fmaf(r2, cw, 1.0f);
  const bool swq = (q & 1) != 0;
  float sb = swq ? cosr : sinr;
  float cb = swq ? sinr : cosr;
  unsigned ssign = ((unsigned)q << 30) & 0x80000000u;
  unsigned csign = ((unsigned)(q + 1) << 30) & 0x80000000u;
  s = __uint_as_float(__float_as_uint(sb) ^ ssign);
  c = __uint_as_float(__float_as_uint(cb) ^ csign);
}

/* ws layout (floats):
   [0, KS*4)            per-k {cost_total, noise[k,0,0], noise[k,0,1], pad}
   [KS*4, KS*4+NBLK)    per-block cost min
   [KS*4+NBLK, +3)      accumulators {sum_w, sum_w*n0, sum_w*n1}            */

__global__ __launch_bounds__(TPB) void mppi_rollout(
    const float* __restrict__ state, const float* __restrict__ U,
    const float* __restrict__ noise, const float* __restrict__ nsi,
    const float* __restrict__ bev,   const float* __restrict__ goal,
    float* __restrict__ ws)
{
  const float MCRf = (float)(tan(30.0 / 57.3) / (0.24 + 0.24) * 20.0 * 0.02);

  __shared__ float  s_bev[2500];
  __shared__ float4 s_ug[97];        /* {u0*MCR, u1*WSM, g0, g1}; [96] = pad */

  const int tid = threadIdx.x;
  if (tid < 97) {
    float u0 = 0.f, u1 = 0.f;
    if (tid < 95) { u0 = U[(tid + 1) * 2 + 0]; u1 = U[(tid + 1) * 2 + 1]; }
    float4 g;
    g.x = u0 * MCRf; g.y = u1 * WSM;
    g.z = u0 * nsi[0] + u1 * nsi[1];
    g.w = u0 * nsi[2] + u1 * nsi[3];
    s_ug[tid] = g;
  }
  for (int i = tid; i < 2500; i += TPB) s_bev[i] = bev[i];
  if (blockIdx.x == 0 && tid < 3) ws[(size_t)KS * 4 + NBLK + tid] = 0.f;
  __syncthreads();

  const int k = blockIdx.x * TPB + tid;
  const float4* __restrict__ nrow = (const float4*)(noise + (size_t)k * (TS * 2));

  const float gx = goal[0], gy = goal[1];
  float x = state[0], y = state[1], yaw = state[5];

  /* noise ring: A = current pair (4 steps), B = +1, C = +2 */
  float4 A0 = nrow[0], A1 = nrow[1];
  float4 B0 = nrow[2], B1 = nrow[3];
  float4 C0 = nrow[4], C1 = nrow[5];
  const float n00 = A0.x, n01 = A0.y;

  /* ug ring: u1..u4 = ug[4i+1 .. 4i+4] for current iter */
  float4 u1 = s_ug[1], u2 = s_ug[2], u3 = s_ug[3], u4 = s_ug[4];

  float craw, sraw, gz, gw;
  {
    float4 u0 = s_ug[0];
    craw = __builtin_fmaf(A0.x, MCRf, u0.x);
    sraw = __builtin_fmaf(A0.y, WSM,  u0.y);
    gz = u0.z; gw = u0.w;
  }
  float c_acc = 0.f, s_acc = 0.f;
  float a0 = 0.f, a1 = 0.f, dist_sum = 0.f, map_sum = 0.f, dlast = 0.f;
  float p0 = 0.f, p1 = 0.f, p2 = 0.f, p3 = 0.f;   /* pending BEV gathers */

/* one timestep; N=noise[t], M=noise[t+1], UGN=ug[t+1], PEND=deferred gather */
#define STEP(N0, N1, M0, M1, UGN, PEND) do {                          \
    float crn = __builtin_fmaf(M0, MCRf, UGN.x);                      \
    float srn = __builtin_fmaf(M1, WSM,  UGN.y);                      \
    c_acc += fminf(fmaxf(crn - craw, -MCRf), MCRf);                   \
    s_acc += fminf(fmaxf(srn - sraw, -MSR),  MSR);                    \
    craw = crn; sraw = srn;                                           \
    a0 = __builtin_fmaf(N0, gz, a0);                                  \
    a1 = __builtin_fmaf(N1, gw, a1);                                  \
    gz = UGN.z; gw = UGN.w;                                           \
    yaw = __builtin_fmaf(s_acc * c_acc, DTF, yaw);                    \
    float sn_, cs_; fast_sincosf(yaw, sn_, cs_);                      \
    float sdt = s_acc * DTF;                                          \
    x = __builtin_fmaf(sdt, cs_, x);                                  \
    y = __builtin_fmaf(sdt, sn_, y);                                  \
    float dx = x - gx, dy = y - gy;                                   \
    dlast = sqrtf(__builtin_fmaf(dy, dy, dx * dx));                   \
    dist_sum += dlast;                                                \
    float fx = fminf(fmaxf(__builtin_fmaf(x, 2.5f, 25.f), 0.f), 49.f);\
    float fy = fminf(fmaxf(__builtin_fmaf(y, 2.5f, 25.f), 0.f), 49.f);\
    int ix = (int)fx, iy = (int)fy;                                   \
    PEND = s_bev[iy * 50 + ix];                                       \
  } while (0)

/* t=95: c,s are the raw (un-rate-limited) last values; no chain update */
#define STEP_LAST(N0, N1, PEND) do {                                  \
    a0 = __builtin_fmaf(N0, gz, a0);                                  \
    a1 = __builtin_fmaf(N1, gw, a1);                                  \
    yaw = __builtin_fmaf(sraw * craw, DTF, yaw);                      \
    float sn_, cs_; fast_sincosf(yaw, sn_, cs_);                      \
    float sdt = sraw * DTF;                                           \
    x = __builtin_fmaf(sdt, cs_, x);                                  \
    y = __builtin_fmaf(sdt, sn_, y);                                  \
    float dx = x - gx, dy = y - gy;                                   \
    dlast = sqrtf(__builtin_fmaf(dy, dy, dx * dx));                   \
    dist_sum += dlast;                                                \
    float fx = fminf(fmaxf(__builtin_fmaf(x, 2.5f, 25.f), 0.f), 49.f);\
    float fy = fminf(fmaxf(__builtin_fmaf(y, 2.5f, 25.f), 0.f), 49.f);\
    int ix = (int)fx, iy = (int)fy;                                   \
    PEND = s_bev[iy * 50 + ix];                                       \
  } while (0)

  for (int i = 0; i < 23; ++i) {
    /* prefetch ug ring for next iter: ug[4i+5 .. 4i+8] (96 is zero pad) */
    const int tb = 4 * i + 5;
    float4 f1 = s_ug[tb], f2 = s_ug[tb + 1], f3 = s_ug[tb + 2], f4 = s_ug[tb + 3];
    map_sum += (p0 + p1) + (p2 + p3);       /* consume last iter's gathers */
    STEP(A0.x, A0.y, A0.z, A0.w, u1, p0);   /* t = 4i   */
    STEP(A0.z, A0.w, A1.x, A1.y, u2, p1);   /* t = 4i+1 */
    STEP(A1.x, A1.y, A1.z, A1.w, u3, p2);   /* t = 4i+2 */
    STEP(A1.z, A1.w, B0.x, B0.y, u4, p3);   /* t = 4i+3 (raw from next pair) */
    u1 = f1; u2 = f2; u3 = f3; u4 = f4;
    A0 = B0; A1 = B1; B0 = C0; B1 = C1;
    int pf = 2 * i + 6; if (pf > 46) pf = 46;   /* pairs 0..47, stay in-bounds */
    C0 = nrow[pf]; C1 = nrow[pf + 1];
  }
  /* epilogue: t = 92..95; A = pairs (46,47); u1..u4 = ug[93..96] */
  map_sum += (p0 + p1) + (p2 + p3);
  STEP(A0.x, A0.y, A0.z, A0.w, u1, p0);     /* t=92 */
  STEP(A0.z, A0.w, A1.x, A1.y, u2, p1);     /* t=93 */
  STEP(A1.x, A1.y, A1.z, A1.w, u3, p2);     /* t=94: crn=raw95, carries g95 */
  STEP_LAST(A1.z, A1.w, p3);                /* t=95 */
  map_sum += (p0 + p1) + (p2 + p3);
#undef STEP
#undef STEP_LAST

  /* terminal = dist at t=95 (dlast) */
  const float cost_total = map_sum + 0.1f * dist_sum + dlast + a0 + a1;

  float4 o; o.x = cost_total; o.y = n00; o.z = n01; o.w = 0.f;
  ((float4*)ws)[k] = o;

  /* block-level min */
  float m = cost_total;
  #pragma unroll
  for (int off = 32; off >= 1; off >>= 1) m = fminf(m, __shfl_xor(m, off));
  __shared__ float s_m[TPB / 64];
  if ((tid & 63) == 0) s_m[tid >> 6] = m;
  __syncthreads();
  if (tid == 0) {
    float bm = s_m[0];
    for (int w = 1; w < TPB / 64; ++w) bm = fminf(bm, s_m[w]);
    ws[(size_t)KS * 4 + blockIdx.x] = bm;
  }
}

__global__ __launch_bounds__(TPB) void mppi_weight(
    const float* __restrict__ ws, float* __restrict__ acc)
{
  const int tid = threadIdx.x;
  /* beta: every block redundantly reduces the 256 block mins (L2-hot) */
  const float* mins = ws + (size_t)KS * 4;
  float m = mins[tid];
  #pragma unroll
  for (int off = 32; off >= 1; off >>= 1) m = fminf(m, __shfl_xor(m, off));
  __shared__ float s_m[TPB / 64];
  if ((tid & 63) == 0) s_m[tid >> 6] = m;
  __syncthreads();
  const float beta = fminf(fminf(s_m[0], s_m[1]), fminf(s_m[2], s_m[3]));

  const int k = blockIdx.x * TPB + tid;
  const float4 v = ((const float4*)ws)[k];
  const float w = expf(beta - v.x);   /* exp(-(cost-beta)/LAMBDA), LAMBDA=1 */
  float s0 = w, s1 = w * v.y, s2 = w * v.z;
  #pragma unroll
  for (int off = 32; off >= 1; off >>= 1) {
    s0 += __shfl_xor(s0, off);
    s1 += __shfl_xor(s1, off);
    s2 += __shfl_xor(s2, off);
  }
  __shared__ float s_p[TPB / 64][3];
  if ((tid & 63) == 0) { s_p[tid >> 6][0] = s0; s_p[tid >> 6][1] = s1; s_p[tid >> 6][2] = s2; }
  __syncthreads();
  if (tid == 0) {
    float b0 = 0.f, b1 = 0.f, b2 = 0.f;
    for (int w2 = 0; w2 < TPB / 64; ++w2) { b0 += s_p[w2][0]; b1 += s_p[w2][1]; b2 += s_p[w2][2]; }
    atomicAdd(&acc[0], b0); atomicAdd(&acc[1], b1); atomicAdd(&acc[2], b2);
  }
}

__global__ void mppi_final(const float* __restrict__ U,
                           const float* __restrict__ acc,
                           float* __restrict__ out)
{
  if (threadIdx.x == 0) {
    const float inv = 1.0f / acc[0];
    out[0] = U[2] + acc[1] * inv;   /* U_rolled[0] = U_orig[1] */
    out[1] = U[3] + acc[2] * inv;
  }
}

extern "C" void kernel_launch(void* const* d_in, const int* in_sizes, int n_in,
                              void* d_out, int out_size, void* d_ws, size_t ws_size,
                              hipStream_t stream)
{
  const float* state = (const float*)d_in[0];
  const float* U     = (const float*)d_in[1];
  const float* noise = (const float*)d_in[2];
  const float* nsi   = (const float*)d_in[3];
  const float* bev   = (const float*)d_in[4];
  const float* goal  = (const float*)d_in[5];
  /* d_in[6] (last_action) only writes state[15:17] -> never affects output */

  float* ws  = (float*)d_ws;
  float* out = (float*)d_out;
  float* acc = ws + (size_t)KS * 4 + NBLK;

  mppi_rollout<<<NBLK, TPB, 0, stream>>>(state, U, noise, nsi, bev, goal, ws);
  mppi_weight<<<NBLK, TPB, 0, stream>>>(ws, acc);
  mppi_final<<<1, 64, 0, stream>>>(U, acc, out);
}